// Round 10
// baseline (35.467 us; speedup 1.0000x reference)
//
#include <hip/hip_runtime.h>
#include <cmath>

#define PH 7
#define PW 7
#define FH 64
#define FW 64
#define CC 512
#define SCALE 0.0625f

typedef float f32x4 __attribute__((ext_vector_type(4)));

static __device__ __forceinline__ f32x4 vmax4(f32x4 a, f32x4 b) {
    f32x4 r;
    r.x = fmaxf(a.x, b.x); r.y = fmaxf(a.y, b.y);
    r.z = fmaxf(a.z, b.z); r.w = fmaxf(a.w, b.w);
    return r;
}

// ---------------------------------------------------------------------------
// Kernel 1: counting sort of ROIs by feature-space start row (64 buckets) AND
// per-ROI geometry precompute: geo[slot] = {bin_h, bin_w,
// bitcast(n | sh<<10 | sw<<17 | bidx<<24), 0}. Bin sizes use the XLA
// reciprocal-multiply form roi/7 -> roi * fl32(1/7) (proven bit-exact, R3).
// ---------------------------------------------------------------------------
__global__ __launch_bounds__(512) void sort_rois_kernel(
        const float* __restrict__ rois, int N, float4* __restrict__ geo) {
    __shared__ int base[64];
    __shared__ int cur[64];
    int t = threadIdx.x;
    if (t < 64) { base[t] = 0; cur[t] = 0; }
    __syncthreads();
    int b = -1, packed = 0;
    float bh = 0.f, bw = 0.f;
    if (t < N) {
        const float* r = rois + (size_t)t * 5;
        int bidx = (int)r[0];
        int sw = (int)rintf(r[1] * SCALE);
        int sh = (int)rintf(r[2] * SCALE);
        int ew = (int)rintf(r[3] * SCALE);
        int eh = (int)rintf(r[4] * SCALE);
        bh = fmaxf((float)(eh - sh + 1), 1.0f) * (1.0f / 7.0f);
        bw = fmaxf((float)(ew - sw + 1), 1.0f) * (1.0f / 7.0f);
        packed = t | (sh << 10) | (sw << 17) | (bidx << 24);
        b = min(max(sh, 0), FH - 1);
        atomicAdd(&base[b], 1);
    }
    __syncthreads();
    if (t == 0) {
        int acc = 0;
        for (int i = 0; i < 64; ++i) { int c = base[i]; base[i] = acc; acc += c; }
    }
    __syncthreads();
    if (t < N) {
        int pos = base[b] + atomicAdd(&cur[b], 1);
        float4 g;
        g.x = bh; g.y = bw; g.z = __int_as_float(packed); g.w = 0.f;
        geo[pos] = g;
    }
}

// ---------------------------------------------------------------------------
// Kernel 2: ONE WAVE PER (sorted roi, ph, channel-half). R8's carry-based
// horizontal dedup (each band cell loaded once; overlap<=1 col and no-gap
// invariants proven + refcheck'd in R8) but with the occupancy bug fixed:
// 7168 waves / 1792 blocks = 7 blocks/CU = 28 waves/CU (R8 had 896 blocks
// = 3.5/CU -> 14% occupancy -> regression). Logical reads 580 -> ~410 MB.
// Inner loop: 2 cols x 2 rows = 4 independent dwordx4 loads per step; the
// +2048B col offset folds into the load immediate. Geometry = bit-exact
// fp32 XLA forms (round 3). Sorted order + bijective XCD-chunk swizzle
// keep each XCD's band in its private 4MB L2 (round 4).
// ---------------------------------------------------------------------------
__global__ __launch_bounds__(256) void roi_pool_kernel(
        const float* __restrict__ feat,
        const float4* __restrict__ geo,
        float* __restrict__ out,
        int nWaves) {
    // bijective XCD-chunk swizzle (HW: XCD = blockIdx % 8); 1792 % 8 == 0
    int p = blockIdx.x, nwg = gridDim.x;
    int q = nwg >> 3, rr = nwg & 7;
    int xcd = p & 7, o = p >> 3;
    int L = (xcd < rr ? xcd * (q + 1) : rr * (q + 1) + (xcd - rr) * q) + o;

    int lane = (int)threadIdx.x & 63;
    int g = __builtin_amdgcn_readfirstlane(L * 4 + ((int)threadIdx.x >> 6));
    if (g >= nWaves) return;
    int s    = g / 14;           // sorted roi slot
    int t    = g - s * 14;
    int ph   = t >> 1;
    int half = t & 1;            // channel half: [half*256, half*256+256)

    float4 gg = geo[s];
    float bh = gg.x, bw = gg.y;
    int packed = __float_as_int(gg.z);
    int n    = packed & 1023;
    int sh   = (packed >> 10) & 127;
    int sw   = (packed >> 17) & 127;
    int bidx = (packed >> 24) & 255;

    int hs = min(max((int)floorf((float)ph * bh) + sh, 0), FH);
    int he = min(max((int)ceilf((float)(ph + 1) * bh) + sh, 0), FH);
    int R  = he - hs;

    float* outB = out + (size_t)(n * 49 + ph * 7) * CC + (size_t)(half * 256 + lane * 4);
    const f32x4 zero4 = {0.f, 0.f, 0.f, 0.f};
    const f32x4 negi  = {-INFINITY, -INFINITY, -INFINITY, -INFINITY};

    if (R <= 0) {  // whole bin-row empty -> reference outputs zeros
        for (int pw = 0; pw < 7; ++pw)
            __builtin_nontemporal_store(zero4, (f32x4*)(outB + pw * CC));
        return;
    }

    const float* fb = feat + (size_t)((bidx * FH + hs) * FW) * CC
                    + (size_t)(half * 256 + lane * 4);
    const int RS = FW * CC;      // feature row stride in floats

    f32x4 vLast = negi;          // col-max of column wdone-1
    int wdone = 0;

    for (int pw = 0; pw < 7; ++pw) {
        int ws = min(max((int)floorf((float)pw * bw) + sw, 0), FW);
        int we = min(max((int)ceilf((float)(pw + 1) * bw) + sw, 0), FW);
        if (we <= ws) {          // clip-empty bin -> zeros
            __builtin_nontemporal_store(zero4, (f32x4*)(outB + pw * CC));
            continue;
        }
        // carry: column wdone-1 is in this bin's window iff wdone > ws
        f32x4 acc = (wdone > ws) ? vLast : negi;
        int w = max(ws, wdone);

        for (; w + 2 <= we; w += 2) {        // 2 cols x 2 rows in flight
            const float* c0 = fb + (size_t)w * CC;
            f32x4 A0 = negi, A1 = negi;
            int r = 0;
            for (; r + 2 <= R; r += 2) {
                const float* p0 = c0 + (size_t)r * RS;
                const float* p1 = p0 + RS;
                f32x4 x0 = *(const f32x4*)p0;  f32x4 y0 = *(const f32x4*)(p0 + CC);
                f32x4 x1 = *(const f32x4*)p1;  f32x4 y1 = *(const f32x4*)(p1 + CC);
                A0 = vmax4(A0, vmax4(x0, x1));
                A1 = vmax4(A1, vmax4(y0, y1));
            }
            if (R & 1) {
                const float* p0 = c0 + (size_t)r * RS;
                A0 = vmax4(A0, *(const f32x4*)p0);
                A1 = vmax4(A1, *(const f32x4*)(p0 + CC));
            }
            acc = vmax4(acc, A0);
            acc = vmax4(acc, A1);
            vLast = A1;                       // col-max of col w+1
        }
        if (w < we) {                         // single tail column
            const float* c0 = fb + (size_t)w * CC;
            f32x4 A0 = negi;
            int r = 0;
            for (; r + 2 <= R; r += 2) {
                const float* p0 = c0 + (size_t)r * RS;
                f32x4 x0 = *(const f32x4*)p0;
                f32x4 x1 = *(const f32x4*)(p0 + RS);
                A0 = vmax4(A0, vmax4(x0, x1));
            }
            if (R & 1)
                A0 = vmax4(A0, *(const f32x4*)(c0 + (size_t)r * RS));
            acc = vmax4(acc, A0);
            vLast = A0;                       // col-max of col we-1
        }
        wdone = we;
        __builtin_nontemporal_store(acc, (f32x4*)(outB + pw * CC));
    }
}

extern "C" void kernel_launch(void* const* d_in, const int* in_sizes, int n_in,
                              void* d_out, int out_size, void* d_ws, size_t ws_size,
                              hipStream_t stream) {
    const float* feat = (const float*)d_in[0];
    const float* rois = (const float*)d_in[1];
    float* out = (float*)d_out;
    float4* geo = (float4*)d_ws;           // 512 * 16B = 8KB scratch

    int N = in_sizes[1] / 5;               // 512 rois
    sort_rois_kernel<<<1, 512, 0, stream>>>(rois, N, geo);

    int nWaves = N * PH * 2;               // 7168: (roi, ph, half)
    int totalThreads = nWaves * 64;
    int block = 256;
    int grid = (totalThreads + block - 1) / block;   // 1792 (%8 == 0)
    roi_pool_kernel<<<grid, block, 0, stream>>>(feat, geo, out, nWaves);
}

// Round 11
// 32.531 us; speedup vs baseline: 1.0902x; 1.0902x over previous
//
#include <hip/hip_runtime.h>
#include <cmath>

#define PH 7
#define PW 7
#define FH 64
#define FW 64
#define CC 512
#define SCALE 0.0625f

typedef float f32x4 __attribute__((ext_vector_type(4)));

static __device__ __forceinline__ f32x4 vmax4(f32x4 a, f32x4 b) {
    f32x4 r;
    r.x = fmaxf(a.x, b.x); r.y = fmaxf(a.y, b.y);
    r.z = fmaxf(a.z, b.z); r.w = fmaxf(a.w, b.w);
    return r;
}

// ---------------------------------------------------------------------------
// Kernel 1: counting sort of ROIs by feature-space start row (64 buckets) AND
// per-ROI geometry precompute: geo[slot] = {bin_h, bin_w,
// bitcast(n | sh<<10 | sw<<17 | bidx<<24), 0}. Bin sizes use the XLA
// reciprocal-multiply form roi/7 -> roi * fl32(1/7) (proven bit-exact, R3).
// ---------------------------------------------------------------------------
__global__ __launch_bounds__(512) void sort_rois_kernel(
        const float* __restrict__ rois, int N, float4* __restrict__ geo) {
    __shared__ int base[64];
    __shared__ int cur[64];
    int t = threadIdx.x;
    if (t < 64) { base[t] = 0; cur[t] = 0; }
    __syncthreads();
    int b = -1, packed = 0;
    float bh = 0.f, bw = 0.f;
    if (t < N) {
        const float* r = rois + (size_t)t * 5;
        int bidx = (int)r[0];
        int sw = (int)rintf(r[1] * SCALE);
        int sh = (int)rintf(r[2] * SCALE);
        int ew = (int)rintf(r[3] * SCALE);
        int eh = (int)rintf(r[4] * SCALE);
        bh = fmaxf((float)(eh - sh + 1), 1.0f) * (1.0f / 7.0f);
        bw = fmaxf((float)(ew - sw + 1), 1.0f) * (1.0f / 7.0f);
        packed = t | (sh << 10) | (sw << 17) | (bidx << 24);
        b = min(max(sh, 0), FH - 1);
        atomicAdd(&base[b], 1);
    }
    __syncthreads();
    if (t == 0) {
        int acc = 0;
        for (int i = 0; i < 64; ++i) { int c = base[i]; base[i] = acc; acc += c; }
    }
    __syncthreads();
    if (t < N) {
        int pos = base[b] + atomicAdd(&cur[b], 1);
        float4 g;
        g.x = bh; g.y = bw; g.z = __int_as_float(packed); g.w = 0.f;
        geo[pos] = g;
    }
}

// ---------------------------------------------------------------------------
// Kernel 2: Caffe ROI max-pool. TWO WAVES PER BIN (half = 256 channels each,
// lane owns exactly one float4): 50176 short uniform waves so per-wave L2
// stalls always have other resident waves to hide behind (R8/R10 proved the
// dedup/carry structures lose: serialized load streams cost more than the
// 30% byte saving buys). Sorted-ROI order + bijective XCD-chunk swizzle
// keep each XCD's reads in its private 4MB L2 (FETCH 112->26 MB, R4).
// Inner loop: 8 independent dwordx4 loads in flight with a geometric
// 8/4/2/1 tail (max 3 extra stall points, no duplicate reads).
// Geometry = bit-exact fp32 XLA forms (R3). Exact grid -> no bounds guard.
// ---------------------------------------------------------------------------
__global__ __launch_bounds__(256, 8) void roi_pool_kernel(
        const float* __restrict__ feat,
        const float4* __restrict__ geo,
        float* __restrict__ out) {
    // bijective XCD-chunk swizzle (HW: XCD = blockIdx % 8); 12544 % 8 == 0
    int p = blockIdx.x, nwg = gridDim.x;
    int q = nwg >> 3;
    int xcd = p & 7, o = p >> 3;
    int L = xcd * q + o;

    int tid = L * 256 + (int)threadIdx.x;
    int wv   = tid >> 6;         // global wave id
    int lane = tid & 63;
    int bin  = wv >> 1;          // two waves per bin
    int half = wv & 1;           // channel half: [half*256, half*256+256)

    int s   = bin / (PH * PW);   // sorted roi slot
    int rem = bin - s * (PH * PW);
    int ph  = rem / PW;
    int pw  = rem - ph * PW;

    float4 g = geo[s];
    float bh = g.x, bw = g.y;
    int packed = __float_as_int(g.z);
    int n    = packed & 1023;
    int sh   = (packed >> 10) & 127;
    int sw   = (packed >> 17) & 127;
    int bidx = (packed >> 24) & 255;

    int hstart = min(max((int)floorf((float)ph * bh) + sh, 0), FH);
    int hend   = min(max((int)ceilf((float)(ph + 1) * bh) + sh, 0), FH);
    int wstart = min(max((int)floorf((float)pw * bw) + sw, 0), FW);
    int wend   = min(max((int)ceilf((float)(pw + 1) * bw) + sw, 0), FW);
    bool empty = (hend <= hstart) || (wend <= wstart);

    f32x4 mx = { -INFINITY, -INFINITY, -INFINITY, -INFINITY };

    if (!empty) {
        const int W = wend - wstart;
        int cells = (hend - hstart) * W;
        const float* ptr = feat + (size_t)bidx * (FH * FW * CC)
                         + (size_t)hstart * (FW * CC) + (size_t)wstart * CC
                         + (size_t)(half * 256 + lane * 4);
        const int stepWrap = (FW - W + 1) * CC;  // last col -> next row start
        int cw = W;  // cols left in current row (incl. current ptr position)

#define ADV() do { if (--cw == 0) { ptr += stepWrap; cw = W; } else ptr += CC; } while (0)

        while (cells >= 8) {     // 8 independent loads in flight
            const float* q0 = ptr; ADV();
            const float* q1 = ptr; ADV();
            const float* q2 = ptr; ADV();
            const float* q3 = ptr; ADV();
            const float* q4 = ptr; ADV();
            const float* q5 = ptr; ADV();
            const float* q6 = ptr; ADV();
            const float* q7 = ptr; ADV();
            f32x4 a0 = *(const f32x4*)q0; f32x4 a1 = *(const f32x4*)q1;
            f32x4 a2 = *(const f32x4*)q2; f32x4 a3 = *(const f32x4*)q3;
            f32x4 a4 = *(const f32x4*)q4; f32x4 a5 = *(const f32x4*)q5;
            f32x4 a6 = *(const f32x4*)q6; f32x4 a7 = *(const f32x4*)q7;
            a0 = vmax4(a0, a1); a2 = vmax4(a2, a3);
            a4 = vmax4(a4, a5); a6 = vmax4(a6, a7);
            mx = vmax4(mx, vmax4(vmax4(a0, a2), vmax4(a4, a6)));
            cells -= 8;
        }
        if (cells & 4) {         // 4 in flight
            const float* q0 = ptr; ADV();
            const float* q1 = ptr; ADV();
            const float* q2 = ptr; ADV();
            const float* q3 = ptr; ADV();
            f32x4 a0 = *(const f32x4*)q0; f32x4 a1 = *(const f32x4*)q1;
            f32x4 a2 = *(const f32x4*)q2; f32x4 a3 = *(const f32x4*)q3;
            mx = vmax4(mx, vmax4(vmax4(a0, a1), vmax4(a2, a3)));
        }
        if (cells & 2) {         // 2 in flight
            const float* q0 = ptr; ADV();
            const float* q1 = ptr; ADV();
            f32x4 a0 = *(const f32x4*)q0; f32x4 a1 = *(const f32x4*)q1;
            mx = vmax4(mx, vmax4(a0, a1));
        }
        if (cells & 1) {
            mx = vmax4(mx, *(const f32x4*)ptr);
        }
#undef ADV
    } else {
        mx = (f32x4){0.f, 0.f, 0.f, 0.f};
    }

    float* op = out + ((size_t)n * (PH * PW) + rem) * CC
              + (size_t)(half * 256 + lane * 4);
    __builtin_nontemporal_store(mx, (f32x4*)op);
}

extern "C" void kernel_launch(void* const* d_in, const int* in_sizes, int n_in,
                              void* d_out, int out_size, void* d_ws, size_t ws_size,
                              hipStream_t stream) {
    const float* feat = (const float*)d_in[0];
    const float* rois = (const float*)d_in[1];
    float* out = (float*)d_out;
    float4* geo = (float4*)d_ws;           // 512 * 16B = 8KB scratch

    int N = in_sizes[1] / 5;               // 512 rois
    sort_rois_kernel<<<1, 512, 0, stream>>>(rois, N, geo);

    int nBins = N * PH * PW;               // 25088
    int totalThreads = nBins * 2 * 64;     // two waves per bin
    int block = 256;
    int grid = totalThreads / block;       // 12544 exactly (%8 == 0)
    roi_pool_kernel<<<grid, block, 0, stream>>>(feat, geo, out);
}